// Round 1
// baseline (99.777 us; speedup 1.0000x reference)
//
#include <hip/hip_runtime.h>
#include <stdint.h>

typedef unsigned long long u64;

#define BATCH 32
#define H 512
#define W 512
#define WPR 8                     // 64-bit words per row
#define WORDS_IMG (H * WPR)       // 4096 words per image
#define NPIX (H * W)              // 262144
#define NWORDS (BATCH * WORDS_IMG)

// ---------------- pack: y(int32 0/1) -> bitboards via 64-bit ballot ----------
__global__ __launch_bounds__(256) void pack_kernel(const int* __restrict__ y,
                                                   u64* __restrict__ words) {
    int gtid = blockIdx.x * blockDim.x + threadIdx.x;
    int lane = gtid & 63;
    int wave = gtid >> 6;
    int nwaves = (gridDim.x * blockDim.x) >> 6;
    for (int w = wave; w < NWORDS; w += nwaves) {
        int v = y[(size_t)w * 64 + lane];
        u64 m = __ballot(v != 0);
        if (lane == 0) words[w] = m;
    }
}

// ---------------- bit-sliced Zhang-Suen sub-iteration ------------------------
__device__ __forceinline__ void fulladd(u64 a, u64 b, u64 c, u64& s, u64& cy) {
    u64 t = a ^ b;
    s = t ^ c;
    cy = (a & b) | (t & c);
}

template<bool FIRST>
__device__ __forceinline__ void compute_sub(const u64* img, int wc, int r0,
                                            u64 nw[8], u64& diff) {
    u64 C[10], L[10], R[10];
    #pragma unroll
    for (int i = 0; i < 10; ++i) {
        int rr = r0 - 1 + i;
        bool valid = (rr >= 0) && (rr < H);
        C[i] = valid ? img[rr * WPR + wc] : 0ull;
        L[i] = (valid && wc > 0) ? img[rr * WPR + wc - 1] : 0ull;
        R[i] = (valid && wc < WPR - 1) ? img[rr * WPR + wc + 1] : 0ull;
    }
    #pragma unroll
    for (int k = 0; k < 8; ++k) {
        // neighbor bitboards: bit i of board X = value of neighbor X of pixel i
        u64 P2 = C[k];                              // N
        u64 P9 = (C[k]   << 1) | (L[k]   >> 63);    // NW
        u64 P3 = (C[k]   >> 1) | (R[k]   << 63);    // NE
        u64 cC = C[k+1];                            // center
        u64 P8 = (C[k+1] << 1) | (L[k+1] >> 63);    // W
        u64 P4 = (C[k+1] >> 1) | (R[k+1] << 63);    // E
        u64 P6 = C[k+2];                            // S
        u64 P7 = (C[k+2] << 1) | (L[k+2] >> 63);    // SW
        u64 P5 = (C[k+2] >> 1) | (R[k+2] << 63);    // SE

        // Bcnt = popcount of 8 neighbors, bit-sliced CSA tree
        u64 s1, c1, s2, c2, s3, c3, ts, tc, us, uc;
        fulladd(P2, P3, P4, s1, c1);
        fulladd(P5, P6, P7, s2, c2);
        s3 = P8 ^ P9; c3 = P8 & P9;
        fulladd(s1, s2, s3, ts, tc);   // ones: ts(w1) tc(w2)
        fulladd(c1, c2, c3, us, uc);   // twos: us(w2) uc(w4)
        u64 vs = us ^ tc, vc = us & tc;        // w2 bit, carry->w4
        u64 w4 = uc ^ vc, w8 = uc & vc;        // w4 bit, w8 bit
        // Bcnt = ts + 2*vs + 4*w4 + 8*w8 ; need 2<=Bcnt<=6
        u64 condB = (vs | w4 | w8) & ~(w8 | (w4 & vs & ts));

        // A == 1: exactly one 0->1 transition around the ring P2..P9,P2
        u64 seen, multi, t;
        t = ~P2 & P3; seen = t;  multi = 0;
        t = ~P3 & P4; multi |= seen & t; seen |= t;
        t = ~P4 & P5; multi |= seen & t; seen |= t;
        t = ~P5 & P6; multi |= seen & t; seen |= t;
        t = ~P6 & P7; multi |= seen & t; seen |= t;
        t = ~P7 & P8; multi |= seen & t; seen |= t;
        t = ~P8 & P9; multi |= seen & t; seen |= t;
        t = ~P9 & P2; multi |= seen & t; seen |= t;
        u64 ex1 = seen & ~multi;

        u64 cond = FIRST ? (~(P2 & P4 & P6) & ~(P4 & P6 & P8))
                         : (~(P2 & P4 & P8) & ~(P2 & P6 & P8));

        u64 rem = cC & condB & ex1 & cond;
        nw[k] = cC & ~rem;
        diff |= nw[k] ^ cC;
    }
}

// --------------- per-image skeletonize + dilate + gt popcount ---------------
__global__ __launch_bounds__(512) void skel_kernel(u64* __restrict__ gwords,
                                                   float* __restrict__ gt_out) {
    __shared__ u64 img[WORDS_IMG];   // 32 KB
    __shared__ int s_changed;
    __shared__ int s_gt;
    const int b = blockIdx.x;
    const int tid = threadIdx.x;
    const int wc = tid & 7;
    const int r0 = (tid >> 3) * 8;   // 64 row-groups * 8 rows
    u64* gimg = gwords + (size_t)b * WORDS_IMG;

    #pragma unroll
    for (int k = 0; k < 8; ++k)
        img[(r0 + k) * WPR + wc] = gimg[(r0 + k) * WPR + wc];
    if (tid == 0) s_changed = 0;
    __syncthreads();

    bool changed = true;
    for (int it = 0; it < 4096 && changed; ++it) {
        u64 diff = 0;
        u64 nw[8];
        compute_sub<true>(img, wc, r0, nw, diff);
        __syncthreads();
        #pragma unroll
        for (int k = 0; k < 8; ++k) img[(r0 + k) * WPR + wc] = nw[k];
        __syncthreads();
        compute_sub<false>(img, wc, r0, nw, diff);
        __syncthreads();
        #pragma unroll
        for (int k = 0; k < 8; ++k) img[(r0 + k) * WPR + wc] = nw[k];
        if (diff) atomicOr(&s_changed, 1);
        __syncthreads();                 // writes + flag visible
        changed = (s_changed != 0);
        __syncthreads();                 // everyone has read flag
        if (tid == 0) s_changed = 0;     // next atomicOr is >=2 barriers away
    }

    // dilate twice with the cross element
    for (int d = 0; d < 2; ++d) {
        u64 nw[8];
        u64 Cc[10];
        #pragma unroll
        for (int i = 0; i < 10; ++i) {
            int rr = r0 - 1 + i;
            Cc[i] = (rr >= 0 && rr < H) ? img[rr * WPR + wc] : 0ull;
        }
        #pragma unroll
        for (int k = 0; k < 8; ++k) {
            int rr = r0 + k;
            u64 lw = (wc > 0)       ? img[rr * WPR + wc - 1] : 0ull;
            u64 rw = (wc < WPR - 1) ? img[rr * WPR + wc + 1] : 0ull;
            u64 c = Cc[k + 1];
            u64 west = (c << 1) | (lw >> 63);
            u64 east = (c >> 1) | (rw << 63);
            nw[k] = c | Cc[k] | Cc[k + 2] | west | east;
        }
        __syncthreads();
        #pragma unroll
        for (int k = 0; k < 8; ++k) img[(r0 + k) * WPR + wc] = nw[k];
        __syncthreads();
    }

    // write final mask + popcount for gt_sum
    int pc = 0;
    #pragma unroll
    for (int k = 0; k < 8; ++k) {
        u64 v = img[(r0 + k) * WPR + wc];
        gimg[(r0 + k) * WPR + wc] = v;
        pc += __popcll(v);
    }
    if (tid == 0) s_gt = 0;
    __syncthreads();
    atomicAdd(&s_gt, pc);
    __syncthreads();
    if (tid == 0) gt_out[b] = (float)s_gt;
}

// --------------- intersection = sum(x * skel) per image, partials -----------
__global__ __launch_bounds__(256) void inter_kernel(const float* __restrict__ x,
                                                    const u64* __restrict__ words,
                                                    float* __restrict__ partial) {
    const int b = blockIdx.x >> 6;       // 64 blocks per image
    const int chunk = blockIdx.x & 63;   // 4096 pixels per block
    const int tid = threadIdx.x;
    const int lane = tid & 63;
    const u64* w = words + (size_t)b * WORDS_IMG;
    const float* xb = x + (size_t)b * NPIX;
    float sum = 0.0f;
    const int qbase = chunk * 4096;
    #pragma unroll
    for (int k = 0; k < 16; ++k) {
        int q = qbase + k * 256 + tid;       // coalesced; word uniform per wave
        u64 word = w[q >> 6];
        if ((word >> lane) & 1ull) sum += xb[q];
    }
    for (int off = 32; off > 0; off >>= 1) sum += __shfl_down(sum, off, 64);
    __shared__ float sred[4];
    if (lane == 0) sred[tid >> 6] = sum;
    __syncthreads();
    if (tid == 0) partial[blockIdx.x] = (sred[0] + sred[1]) + (sred[2] + sred[3]);
}

// --------------- final: recall per image, mean, negate ----------------------
__global__ __launch_bounds__(64) void final_kernel(const float* __restrict__ partial,
                                                   const float* __restrict__ gt,
                                                   float* __restrict__ out) {
    __shared__ float rec[32];
    int tid = threadIdx.x;
    if (tid < 32) {
        float inter = 0.0f;
        for (int j = 0; j < 64; ++j) inter += partial[tid * 64 + j];
        rec[tid] = (inter + 1.0f) / (gt[tid] + 1.0f);
    }
    __syncthreads();
    if (tid == 0) {
        float s = 0.0f;
        for (int i = 0; i < 32; ++i) s += rec[i];
        out[0] = -(s / 32.0f);
    }
}

extern "C" void kernel_launch(void* const* d_in, const int* in_sizes, int n_in,
                              void* d_out, int out_size, void* d_ws, size_t ws_size,
                              hipStream_t stream) {
    const float* x = (const float*)d_in[0];
    const int*   y = (const int*)d_in[1];
    float* out = (float*)d_out;

    u64*   words   = (u64*)d_ws;                                   // 1 MiB
    float* gt      = (float*)((char*)d_ws + (size_t)NWORDS * 8);   // 32 f
    float* partial = gt + 32;                                      // 2048 f

    pack_kernel<<<512, 256, 0, stream>>>(y, words);
    skel_kernel<<<BATCH, 512, 0, stream>>>(words, gt);
    inter_kernel<<<BATCH * 64, 256, 0, stream>>>(x, words, partial);
    final_kernel<<<1, 64, 0, stream>>>(partial, gt, out);
}